// Round 14
// baseline (322.349 us; speedup 1.0000x reference)
//
#include <hip/hip_runtime.h>
#include <math.h>

#define Bdim 8
#define Tdim 12
#define BT   96
#define Ndim 1024
#define Cdim 64
#define Ddim 10
#define Jdim 6144      // BT*C
#define IOdim 4096     // C*C

typedef __attribute__((ext_vector_type(4))) float f32x4;
typedef __attribute__((ext_vector_type(8))) short bf16x8;
typedef __attribute__((ext_vector_type(4))) _Float16 f16x4;

__device__ inline short f2bf(float f) {
    union { float f; unsigned u; } v; v.f = f;
    return (short)((v.u + 0x8000u) >> 16);
}
__device__ inline float bf2f(short s) {
    union { float f; unsigned u; } v; v.u = ((unsigned)(unsigned short)s) << 16;
    return v.f;
}
__device__ inline void load_lds16(const void* g, void* l) {
    __builtin_amdgcn_global_load_lds(
        (const __attribute__((address_space(1))) unsigned int*)g,
        (__attribute__((address_space(3))) unsigned int*)l, 16, 0, 0);
}
// fast exp / rcp / log (native v_exp_f32 / v_rcp_f32 / v_log_f32)
__device__ inline float fexp(float x) { return __expf(x); }
__device__ inline float frcp(float x) { return __builtin_amdgcn_rcpf(x); }
__device__ inline float flog(float x) { return __logf(x); }

// ---------------------------------------------------------------- supports (bf16)
__global__ __launch_bounds__(256) void k_supports(
    const float* __restrict__ e1, const float* __restrict__ e2,
    short* __restrict__ Sbf)
{
    int idx = blockIdx.x * 256 + threadIdx.x;
    int i = idx >> 10, j = idx & 1023;
    float s = 0.f;
#pragma unroll
    for (int d = 0; d < Ddim; ++d)
        s += e1[i * Ddim + d] * e2[j * Ddim + d]
           - e2[i * Ddim + d] * e1[j * Ddim + d];
    float t = 1.f - 2.f * frcp(fexp(2.f * s) + 1.f);
    float v = fmaxf(t, 0.f);
    if (i == j) v += 1.f;
    Sbf[idx] = f2bf(v);
}

// ---------------------------------------------------------------- row softmax (bf16 out)
__global__ __launch_bounds__(256) void k_softmax_rows(
    const float* __restrict__ In, short* __restrict__ Out)
{
    int row = blockIdx.x;
    const float* r = In + (size_t)row * Ndim;
    short* o = Out + (size_t)row * Ndim;
    __shared__ float red[256];
    int tid = threadIdx.x;
    float vals[4];
    float lmax = -INFINITY;
#pragma unroll
    for (int i = 0; i < 4; ++i) { vals[i] = r[tid + 256 * i]; lmax = fmaxf(lmax, vals[i]); }
    red[tid] = lmax; __syncthreads();
    for (int s = 128; s > 0; s >>= 1) {
        if (tid < s) red[tid] = fmaxf(red[tid], red[tid + s]);
        __syncthreads();
    }
    float m = red[0]; __syncthreads();
    float lsum = 0.f;
#pragma unroll
    for (int i = 0; i < 4; ++i) { vals[i] = fexp(vals[i] - m); lsum += vals[i]; }
    red[tid] = lsum; __syncthreads();
    for (int s = 128; s > 0; s >>= 1) {
        if (tid < s) red[tid] += red[tid + s];
        __syncthreads();
    }
    float inv = frcp(red[0]);
#pragma unroll
    for (int i = 0; i < 4; ++i) o[tid + 256 * i] = f2bf(vals[i] * inv);
}

// ---------------------------------------------------------------- x -> xbf + xT bf16
__global__ __launch_bounds__(256) void k_cvt_x(
    const float* __restrict__ x, short* __restrict__ xbf, short* __restrict__ xT)
{
    __shared__ float Lt[64][65];
    int bt = blockIdx.y, n0 = blockIdx.x * 64;
    const float* src = x + (size_t)bt * 65536 + (size_t)n0 * 64;
    int tid = threadIdx.x;
#pragma unroll
    for (int p = 0; p < 4; ++p) {
        int idx = p * 256 + tid;
        int r = idx >> 4, c4 = idx & 15;
        float4 v = *(const float4*)&src[r * 64 + c4 * 4];
        short4 s4 = make_short4(f2bf(v.x), f2bf(v.y), f2bf(v.z), f2bf(v.w));
        *(short4*)&xbf[(size_t)bt * 65536 + (size_t)(n0 + r) * 64 + c4 * 4] = s4;
        Lt[r][c4 * 4 + 0] = v.x; Lt[r][c4 * 4 + 1] = v.y;
        Lt[r][c4 * 4 + 2] = v.z; Lt[r][c4 * 4 + 3] = v.w;
    }
    __syncthreads();
#pragma unroll
    for (int p = 0; p < 4; ++p) {
        int idx = p * 256 + tid;
        int c = idx >> 4, k4 = idx & 15;
        short4 s4 = make_short4(f2bf(Lt[k4 * 4 + 0][c]), f2bf(Lt[k4 * 4 + 1][c]),
                                f2bf(Lt[k4 * 4 + 2][c]), f2bf(Lt[k4 * 4 + 3][c]));
        *(short4*)&xT[(size_t)bt * 65536 + (size_t)c * 1024 + n0 + k4 * 4] = s4;
    }
}

// ---------------------------------------------------------------- wpool -> wpT bf16 (4096x1024)
__global__ __launch_bounds__(256) void k_cvt_wp(
    const float* __restrict__ wp, short* __restrict__ wpT)
{
    __shared__ float Lt[64][65];
    int k0 = blockIdx.y * 64, j0 = blockIdx.x * 64;
    int tid = threadIdx.x;
#pragma unroll
    for (int p = 0; p < 4; ++p) {
        int idx = p * 256 + tid;
        int r = idx >> 4, c4 = idx & 15;
        float4 v = *(const float4*)&wp[(size_t)(k0 + r) * IOdim + j0 + c4 * 4];
        Lt[r][c4 * 4 + 0] = v.x; Lt[r][c4 * 4 + 1] = v.y;
        Lt[r][c4 * 4 + 2] = v.z; Lt[r][c4 * 4 + 3] = v.w;
    }
    __syncthreads();
#pragma unroll
    for (int p = 0; p < 4; ++p) {
        int idx = p * 256 + tid;
        int c = idx >> 4, k4 = idx & 15;
        short4 s4 = make_short4(f2bf(Lt[k4 * 4 + 0][c]), f2bf(Lt[k4 * 4 + 1][c]),
                                f2bf(Lt[k4 * 4 + 2][c]), f2bf(Lt[k4 * 4 + 3][c]));
        *(short4*)&wpT[(size_t)(j0 + c) * 1024 + k0 + k4 * 4] = s4;
    }
}

// ---------------------------------------------------------------- bpool (1024x64 f32) -> bpT (64x1024 bf16)
__global__ __launch_bounds__(256) void k_cvt_bp(
    const float* __restrict__ bp, short* __restrict__ bpT)
{
    __shared__ float Lt[64][65];
    int k0 = blockIdx.x * 64;
    int tid = threadIdx.x;
#pragma unroll
    for (int p = 0; p < 4; ++p) {
        int idx = p * 256 + tid;
        int r = idx >> 4, c4 = idx & 15;
        float4 v = *(const float4*)&bp[(size_t)(k0 + r) * 64 + c4 * 4];
        Lt[r][c4 * 4 + 0] = v.x; Lt[r][c4 * 4 + 1] = v.y;
        Lt[r][c4 * 4 + 2] = v.z; Lt[r][c4 * 4 + 3] = v.w;
    }
    __syncthreads();
#pragma unroll
    for (int p = 0; p < 4; ++p) {
        int idx = p * 256 + tid;
        int c = idx >> 4, k4 = idx & 15;       // c = o-row, k4 = k-chunk
        short4 s4 = make_short4(f2bf(Lt[k4 * 4 + 0][c]), f2bf(Lt[k4 * 4 + 1][c]),
                                f2bf(Lt[k4 * 4 + 2][c]), f2bf(Lt[k4 * 4 + 3][c]));
        *(short4*)&bpT[(size_t)c * 1024 + k0 + k4 * 4] = s4;
    }
}

// ---------------------------------------------------------------- m97-style bf16 GEMM, C = A @ B^T
template<int MODE>
__global__ __launch_bounds__(256) void k_gemm_bt(
    const short* __restrict__ A, const short* __restrict__ Bm,
    float* __restrict__ Cf, short* __restrict__ Cb,
    const float* __restrict__ gamma_p)
{
    __shared__ short At[128 * 64];
    __shared__ short Bt[128 * 64];
    const int tid = threadIdx.x;
    const int w = tid >> 6, l = tid & 63;
    const int l15 = l & 15, q = l >> 4;
    const int n0 = blockIdx.x * 128, j0 = blockIdx.y * 128;
    const int wr = (w & 1) * 64, wc = (w >> 1) * 64;
    const int lrow = l >> 3, lc8 = l & 7;

    f32x4 acc[4][4];
#pragma unroll
    for (int i = 0; i < 4; ++i)
#pragma unroll
        for (int j = 0; j < 4; ++j) acc[i][j] = (f32x4)0.f;

    for (int k0 = 0; k0 < 1024; k0 += 64) {
        __syncthreads();
#pragma unroll
        for (int p = 0; p < 4; ++p) {
            int r = p * 32 + w * 8 + lrow;
            int sc = lc8 ^ (r & 7);
            load_lds16(A + (size_t)(n0 + r) * 1024 + k0 + sc * 8,
                       &At[(p * 32 + w * 8) * 64]);
            load_lds16(Bm + (size_t)(j0 + r) * 1024 + k0 + sc * 8,
                       &Bt[(p * 32 + w * 8) * 64]);
        }
        __syncthreads();
#pragma unroll
        for (int ks = 0; ks < 2; ++ks) {
            bf16x8 af[4], bf[4];
#pragma unroll
            for (int rt = 0; rt < 4; ++rt) {
                int row = wr + rt * 16 + l15;
                int pos = (ks * 4 + q) ^ (row & 7);
                af[rt] = *(const bf16x8*)&At[row * 64 + pos * 8];
            }
#pragma unroll
            for (int ct = 0; ct < 4; ++ct) {
                int row = wc + ct * 16 + l15;
                int pos = (ks * 4 + q) ^ (row & 7);
                bf[ct] = *(const bf16x8*)&Bt[row * 64 + pos * 8];
            }
#pragma unroll
            for (int rt = 0; rt < 4; ++rt)
#pragma unroll
                for (int ct = 0; ct < 4; ++ct)
                    acc[rt][ct] = __builtin_amdgcn_mfma_f32_16x16x32_bf16(
                        af[rt], bf[ct], acc[rt][ct], 0, 0, 0);
        }
    }

    float gmm = (MODE == 0) ? gamma_p[0] : 0.f;
#pragma unroll
    for (int rt = 0; rt < 4; ++rt) {
        int nr = n0 + wr + rt * 16 + q * 4;
#pragma unroll
        for (int ct = 0; ct < 4; ++ct) {
            int j = j0 + wc + ct * 16 + l15;
#pragma unroll
            for (int r = 0; r < 4; ++r) {
                float v = acc[rt][ct][r];
                int n = nr + r;
                if (MODE == 1) {
                    Cb[(size_t)n * IOdim + j] = f2bf(v);
                } else if (n < 1024) {
                    int bt = j >> 6, c = j & 63;
                    Cf[(size_t)bt * 65536 + (size_t)n * 64 + c] = gmm * fmaxf(v, 0.f);
                } else {
                    Cb[(size_t)(n - 1024) * Jdim + j] = f2bf(v);
                }
            }
        }
    }
}

// ---------------------------------------------------------------- SA phase 1: L = logsumexp_t S (f16 out)
// r10-proven geometry (64x64 tile, 256 threads, 2048 blocks = full occupancy), f16 out.
__global__ __launch_bounds__(256, 4) void k_sa_z(
    const short* __restrict__ xbf, short* __restrict__ Lh)
{
    __shared__ short Xn[64 * 64];
    __shared__ short Xm[64 * 64];

    int id = blockIdx.x;
    int b = id & 7;
    int r = id >> 3;                     // 0..255
    int tn = r & 15, tm = r >> 4;
    int tid = threadIdx.x;
    int w = tid >> 6, l = tid & 63;
    int l15 = l & 15, q = l >> 4;
    int lrow = l >> 3, lc8 = l & 7;
    int n0 = tn * 64, m0 = tm * 64;
    int wn = (w & 1) * 32, wm = (w >> 1) * 32;

    const short* Xb = xbf + (size_t)b * Tdim * Ndim * Cdim;
    short* Lb = Lh + ((size_t)b << 20);

    f32x4 M[2][2], Z[2][2];
#pragma unroll
    for (int nh = 0; nh < 2; ++nh)
#pragma unroll
        for (int mh = 0; mh < 2; ++mh) { M[nh][mh] = (f32x4)(-INFINITY); Z[nh][mh] = (f32x4)0.f; }

    for (int t = 0; t < Tdim; ++t) {
        const short* xt = Xb + (size_t)t * (Ndim * Cdim);
        __syncthreads();                 // protect prev-iter LDS reads
#pragma unroll
        for (int p = 0; p < 2; ++p) {
            int rr = p * 32 + w * 8 + lrow;
            int sc = lc8 ^ (rr & 7);
            load_lds16(xt + (size_t)(n0 + rr) * 64 + sc * 8, &Xn[(p * 32 + w * 8) * 64]);
            load_lds16(xt + (size_t)(m0 + rr) * 64 + sc * 8, &Xm[(p * 32 + w * 8) * 64]);
        }
        __syncthreads();

        f32x4 sacc[2][2];
        sacc[0][0] = (f32x4)0.f; sacc[0][1] = (f32x4)0.f;
        sacc[1][0] = (f32x4)0.f; sacc[1][1] = (f32x4)0.f;
#pragma unroll
        for (int ch = 0; ch < 2; ++ch) {
            bf16x8 qb[2], af[2];
#pragma unroll
            for (int nh = 0; nh < 2; ++nh) {
                int row = wn + nh * 16 + l15;
                int pos = (ch * 4 + q) ^ (row & 7);
                qb[nh] = *(const bf16x8*)&Xn[row * 64 + pos * 8];
            }
#pragma unroll
            for (int mh = 0; mh < 2; ++mh) {
                int row = wm + mh * 16 + l15;
                int pos = (ch * 4 + q) ^ (row & 7);
                af[mh] = *(const bf16x8*)&Xm[row * 64 + pos * 8];
            }
#pragma unroll
            for (int nh = 0; nh < 2; ++nh)
#pragma unroll
                for (int mh = 0; mh < 2; ++mh)
                    sacc[nh][mh] = __builtin_amdgcn_mfma_f32_16x16x32_bf16(
                        af[mh], qb[nh], sacc[nh][mh], 0, 0, 0);
        }
        // online LSE update
#pragma unroll
        for (int nh = 0; nh < 2; ++nh)
#pragma unroll
            for (int mh = 0; mh < 2; ++mh)
#pragma unroll
                for (int i = 0; i < 4; ++i) {
                    float s  = sacc[nh][mh][i];
                    float mo = M[nh][mh][i];
                    float mn = fmaxf(mo, s);
                    Z[nh][mh][i] = Z[nh][mh][i] * fexp(mo - mn) + fexp(s - mn);
                    M[nh][mh][i] = mn;
                }
    }
#pragma unroll
    for (int nh = 0; nh < 2; ++nh)
#pragma unroll
        for (int mh = 0; mh < 2; ++mh) {
            f16x4 ev;
#pragma unroll
            for (int i = 0; i < 4; ++i)
                ev[i] = (_Float16)(M[nh][mh][i] + flog(Z[nh][mh][i]));
            *(f16x4*)&Lb[(size_t)(n0 + wn + nh * 16 + l15) * 1024
                         + m0 + wm + mh * 16 + q * 4] = ev;
        }
}

// ---------------------------------------------------------------- SA phase 2: out += beta*relu(PV)
// r13 falsifier: T14 prefetch alone was null -> the 64-barrier phase structure is the
// convoy term (3 blocks/CU, grid-limited). This round: m-tile 32->64 (16 iters) +
// single-barrier double-buffered LDS => 16 barriers/block (was 64). Staged bytes,
// e-bytes, MFMA count unchanged. LDS 45 KB (3 blocks/CU by LDS == grid's 3).
__global__ __launch_bounds__(256, 3) void k_sa_pv(
    const short* __restrict__ xbf, const short* __restrict__ xT,
    const short* __restrict__ Lh, float* __restrict__ Out,
    const float* __restrict__ beta_p)
{
    __shared__ short Xm[2][64 * 72];     // [buf][m][c], row stride 72 shorts
    __shared__ short XTl[2][64 * 72];    // [buf][c][m], row stride 72 shorts
    __shared__ short Pl[4][16][72];      // [wave][n][m-shorts], wave-private

    int id = blockIdx.x;
    int b = id & 7;
    int r = id >> 3;                     // 0..95
    int nt = r & 7, t = r >> 3;
    int tid = threadIdx.x;
    int w = tid >> 6, l = tid & 63;
    int l15 = l & 15, q = l >> 4;
    int n0 = nt * 128 + w * 32;

    const short* Xb  = xbf + ((size_t)b * Tdim + t) * (Ndim * Cdim);
    const short* XTb = xT  + ((size_t)b * Tdim + t) * (Ndim * Cdim);
    const short* Lb  = Lh + ((size_t)b << 20);

    int srow = tid >> 2, sc4 = tid & 3;  // staging: 64 rows x (2 passes x 4) 16B chunks

    // Q B-fragments cached across the m sweep
    bf16x8 qf[2][2];
#pragma unroll
    for (int nh = 0; nh < 2; ++nh)
#pragma unroll
        for (int ch = 0; ch < 2; ++ch)
            qf[nh][ch] = *(const bf16x8*)&Xb[(n0 + nh * 16 + l15) * 64 + ch * 32 + q * 8];

    f32x4 oacc[2][4];
#pragma unroll
    for (int nh = 0; nh < 2; ++nh)
#pragma unroll
        for (int ct = 0; ct < 4; ++ct) oacc[nh][ct] = (f32x4)0.f;

    // preload tile 0 into regs
    bf16x8 v[2], v2[2];
#pragma unroll
    for (int p = 0; p < 2; ++p) {
        v[p]  = *(const bf16x8*)&Xb[(size_t)srow * 64 + (sc4 + 4 * p) * 8];
        v2[p] = *(const bf16x8*)&XTb[(size_t)srow * 1024 + (sc4 + 4 * p) * 8];
    }

    for (int mi = 0; mi < 16; ++mi) {
        int cur = mi & 1;
        int m0 = mi * 64;
        // ---- write tile mi into buf[cur] (safe: buf[cur]'s old content, tile mi-2,
        // was read in iter mi-2, before the iter mi-1 barrier)
#pragma unroll
        for (int p = 0; p < 2; ++p) {
            *(bf16x8*)&Xm[cur][srow * 72 + (sc4 + 4 * p) * 8]  = v[p];
            *(bf16x8*)&XTl[cur][srow * 72 + (sc4 + 4 * p) * 8] = v2[p];
        }
        // ---- prefetch tile mi+1 (lands during barrier + compute)
        int m0n = (mi < 15) ? m0 + 64 : m0;
#pragma unroll
        for (int p = 0; p < 2; ++p) {
            v[p]  = *(const bf16x8*)&Xb[(size_t)(m0n + srow) * 64 + (sc4 + 4 * p) * 8];
            v2[p] = *(const bf16x8*)&XTb[(size_t)srow * 1024 + m0n + (sc4 + 4 * p) * 8];
        }
        // ---- e loads for this iter (global, land under scores compute)
        f16x4 e[2][4];
#pragma unroll
        for (int nh = 0; nh < 2; ++nh)
#pragma unroll
            for (int mh = 0; mh < 4; ++mh)
                e[nh][mh] = *(const f16x4*)&Lb[(size_t)(n0 + nh * 16 + l15) * 1024
                                               + m0 + mh * 16 + q * 4];
        __syncthreads();                 // single barrier per iter

        // ---- scores from Xm[cur] (S[n32][m64])
        f32x4 sacc[2][4];
#pragma unroll
        for (int nh = 0; nh < 2; ++nh)
#pragma unroll
            for (int mh = 0; mh < 4; ++mh) sacc[nh][mh] = (f32x4)0.f;
#pragma unroll
        for (int ch = 0; ch < 2; ++ch) {
#pragma unroll
            for (int mh = 0; mh < 4; ++mh) {
                bf16x8 af = *(const bf16x8*)&Xm[cur][(mh * 16 + l15) * 72 + ch * 32 + q * 8];
                sacc[0][mh] = __builtin_amdgcn_mfma_f32_16x16x32_bf16(
                    af, qf[0][ch], sacc[0][mh], 0, 0, 0);
                sacc[1][mh] = __builtin_amdgcn_mfma_f32_16x16x32_bf16(
                    af, qf[1][ch], sacc[1][mh], 0, 0, 0);
            }
        }
        // ---- per nh: p = exp(S-L) pack (64 m) -> wave-private Pl -> PV (2 ks)
#pragma unroll
        for (int nh = 0; nh < 2; ++nh) {
#pragma unroll
            for (int mh = 0; mh < 4; ++mh) {
                f32x4 p = sacc[nh][mh];
                f16x4 ee = e[nh][mh];
                unsigned u0 = (unsigned)(unsigned short)f2bf(fexp(p[0] - (float)ee[0]))
                            | ((unsigned)(unsigned short)f2bf(fexp(p[1] - (float)ee[1])) << 16);
                unsigned u1 = (unsigned)(unsigned short)f2bf(fexp(p[2] - (float)ee[2]))
                            | ((unsigned)(unsigned short)f2bf(fexp(p[3] - (float)ee[3])) << 16);
                *(uint2*)&Pl[w][l15][mh * 16 + q * 4] = make_uint2(u0, u1);
            }
#pragma unroll
            for (int ks = 0; ks < 2; ++ks) {
                bf16x8 pf = *(const bf16x8*)&Pl[w][l15][ks * 32 + q * 8];
#pragma unroll
                for (int ct = 0; ct < 4; ++ct) {
                    bf16x8 bfr = *(const bf16x8*)&XTl[cur][(ct * 16 + l15) * 72 + ks * 32 + q * 8];
                    oacc[nh][ct] = __builtin_amdgcn_mfma_f32_16x16x32_bf16(
                        pf, bfr, oacc[nh][ct], 0, 0, 0);
                }
            }
        }
    }

    float beta = beta_p[0];
#pragma unroll
    for (int nh = 0; nh < 2; ++nh)
#pragma unroll
        for (int ct = 0; ct < 4; ++ct)
#pragma unroll
            for (int r2 = 0; r2 < 4; ++r2) {
                size_t idx = (((size_t)b * Tdim + t) * Ndim + n0 + nh * 16 + q * 4 + r2) * Cdim
                           + ct * 16 + l15;
                Out[idx] += beta * fmaxf(oacc[nh][ct][r2], 0.f);
            }
}

// ---------------------------------------------------------------- bias = S @ bpool via MFMA
__global__ __launch_bounds__(256) void k_bias(
    const short* __restrict__ Sbf, const short* __restrict__ bpT,
    float* __restrict__ bias)
{
    int tid = threadIdx.x;
    int w = tid >> 6, l = tid & 63;
    int l15 = l & 15, q = l >> 4;
    int nr = blockIdx.x * 64 + w * 16;

    f32x4 acc[4];
#pragma unroll
    for (int ct = 0; ct < 4; ++ct) acc[ct] = (f32x4)0.f;

    for (int k0 = 0; k0 < 1024; k0 += 32) {
        bf16x8 af = *(const bf16x8*)&Sbf[(size_t)(nr + l15) * 1024 + k0 + q * 8];
#pragma unroll
        for (int ct = 0; ct < 4; ++ct) {
            bf16x8 bf = *(const bf16x8*)&bpT[(size_t)(ct * 16 + l15) * 1024 + k0 + q * 8];
            acc[ct] = __builtin_amdgcn_mfma_f32_16x16x32_bf16(af, bf, acc[ct], 0, 0, 0);
        }
    }
#pragma unroll
    for (int ct = 0; ct < 4; ++ct)
#pragma unroll
        for (int r = 0; r < 4; ++r)
            bias[(size_t)(nr + q * 4 + r) * 64 + ct * 16 + l15] = acc[ct][r];
}

// ---------------------------------------------------------------- gconv via MFMA (6 waves)
__global__ __launch_bounds__(384) void k_gconv(
    const short* __restrict__ xgT, const short* __restrict__ Wb,
    const float* __restrict__ bias, float* __restrict__ Out,
    const float* __restrict__ alpha_p)
{
    __shared__ short Wl[64 * 64];
    int n = blockIdx.x;
    int tid = threadIdx.x;
    for (int f = tid; f < 512; f += 384) {
        int k = f >> 3, j = f & 7;
        *(bf16x8*)&Wl[k * 64 + (j ^ ((k >> 3) & 7)) * 8] =
            *(const bf16x8*)&Wb[(size_t)n * IOdim + f * 8];
    }
    __syncthreads();
    int w = tid / 64, l = tid & 63, l15 = l & 15, q = l >> 4;
    f32x4 acc[4];
#pragma unroll
    for (int ct = 0; ct < 4; ++ct) acc[ct] = (f32x4)0.f;
    const short* xr = xgT + (size_t)n * Jdim + (size_t)(w * 16 + l15) * 64;
#pragma unroll
    for (int ks = 0; ks < 2; ++ks) {
        bf16x8 a = *(const bf16x8*)&xr[ks * 32 + q * 8];
        int kb = ks * 32 + q * 8;
        int msk = (kb >> 3) & 7;
#pragma unroll
        for (int ct = 0; ct < 4; ++ct) {
            bf16x8 bfr;
#pragma unroll
            for (int e = 0; e < 8; ++e) {
                int o = ct * 16 + l15;
                bfr[e] = Wl[(kb + e) * 64 + (((o >> 3) ^ msk) * 8) + (o & 7)];
            }
            acc[ct] = __builtin_amdgcn_mfma_f32_16x16x32_bf16(a, bfr, acc[ct], 0, 0, 0);
        }
    }
    float alpha = alpha_p[0];
#pragma unroll
    for (int ct = 0; ct < 4; ++ct) {
        int o = ct * 16 + l15;
        float bo = bias[(size_t)n * 64 + o];
#pragma unroll
        for (int r = 0; r < 4; ++r) {
            int bt = w * 16 + q * 4 + r;
            size_t idx = (size_t)bt * 65536 + (size_t)n * 64 + o;
            Out[idx] += alpha * fmaxf(acc[ct][r] + bo, 0.f);
        }
    }
}

// ---------------------------------------------------------------- launch
extern "C" void kernel_launch(void* const* d_in, const int* in_sizes, int n_in,
                              void* d_out, int out_size, void* d_ws, size_t ws_size,
                              hipStream_t stream)
{
    const float* x     = (const float*)d_in[0];
    const float* e1    = (const float*)d_in[1];
    const float* e2    = (const float*)d_in[2];
    const float* Asym  = (const float*)d_in[3];
    const float* wpool = (const float*)d_in[4];
    const float* bpool = (const float*)d_in[5];
    const float* alpha = (const float*)d_in[6];
    const float* beta  = (const float*)d_in[7];
    const float* gamma = (const float*)d_in[8];
    float* out = (float*)d_out;

    short* ASbf = (short*)d_ws;                       // 2048x1024   (4 MB)
    short* xbf  = ASbf + 2048 * 1024;                 // 12.6 MB
    short* xT   = xbf  + 6291456;                     // 12.6 MB
    short* wpT  = xT   + 6291456;                     // 8.4 MB
    short* Wbf  = wpT  + 4194304;                     // 8.4 MB
    short* xgT  = Wbf  + 4194304;                     // 12.6 MB
    float* bias = (float*)(xgT + 6291456);            // 256 KB
    short* Lh   = (short*)(bias + 65536);             // 16.8 MB (logsumexp_t, f16)
    short* bpT  = Lh + 8388608;                       // 128 KB (bpool^T bf16)

    k_supports<<<4096, 256, 0, stream>>>(e1, e2, ASbf + 1024 * 1024);
    k_softmax_rows<<<1024, 256, 0, stream>>>(Asym, ASbf);
    k_cvt_x<<<dim3(16, 96), 256, 0, stream>>>(x, xbf, xT);
    k_cvt_wp<<<dim3(64, 16), 256, 0, stream>>>(wpool, wpT);
    k_cvt_bp<<<16, 256, 0, stream>>>(bpool, bpT);
    // SA phase 1: r10 geometry (64x64, full occupancy), f16 L out
    k_sa_z<<<2048, 256, 0, stream>>>(xbf, Lh);
    // stacked: rows 0..1023 -> out = gamma*relu(A@x); rows 1024..2047 -> xgT = S@x
    k_gemm_bt<0><<<dim3(16, 48), 256, 0, stream>>>(ASbf, xT, out, xgT, gamma);
    // Wbf = S @ wpool
    k_gemm_bt<1><<<dim3(8, 32), 256, 0, stream>>>(ASbf + 1024 * 1024, wpT, nullptr, Wbf, nullptr);
    // bias = S @ bpool (MFMA, L2-resident)
    k_bias<<<16, 256, 0, stream>>>(ASbf + 1024 * 1024, bpT, bias);
    // SA phase 2: out += beta*relu(PV); MT64 + single-barrier double-buffer
    k_sa_pv<<<768, 256, 0, stream>>>(xbf, xT, Lh, out, beta);
    // out += alpha * relu(xgT @ W[n] + bias[n])
    k_gconv<<<1024, 384, 0, stream>>>(xgT, Wbf, bias, out, alpha);
}

// Round 15
// 311.940 us; speedup vs baseline: 1.0334x; 1.0334x over previous
//
#include <hip/hip_runtime.h>
#include <math.h>

#define Bdim 8
#define Tdim 12
#define BT   96
#define Ndim 1024
#define Cdim 64
#define Ddim 10
#define Jdim 6144      // BT*C
#define IOdim 4096     // C*C

typedef __attribute__((ext_vector_type(4))) float f32x4;
typedef __attribute__((ext_vector_type(8))) short bf16x8;
typedef __attribute__((ext_vector_type(4))) _Float16 f16x4;

__device__ inline short f2bf(float f) {
    union { float f; unsigned u; } v; v.f = f;
    return (short)((v.u + 0x8000u) >> 16);
}
__device__ inline float bf2f(short s) {
    union { float f; unsigned u; } v; v.u = ((unsigned)(unsigned short)s) << 16;
    return v.f;
}
__device__ inline void load_lds16(const void* g, void* l) {
    __builtin_amdgcn_global_load_lds(
        (const __attribute__((address_space(1))) unsigned int*)g,
        (__attribute__((address_space(3))) unsigned int*)l, 16, 0, 0);
}
// fast exp / rcp / log (native v_exp_f32 / v_rcp_f32 / v_log_f32)
__device__ inline float fexp(float x) { return __expf(x); }
__device__ inline float frcp(float x) { return __builtin_amdgcn_rcpf(x); }
__device__ inline float flog(float x) { return __logf(x); }

// ---------------------------------------------------------------- supports (bf16)
__global__ __launch_bounds__(256) void k_supports(
    const float* __restrict__ e1, const float* __restrict__ e2,
    short* __restrict__ Sbf)
{
    int idx = blockIdx.x * 256 + threadIdx.x;
    int i = idx >> 10, j = idx & 1023;
    float s = 0.f;
#pragma unroll
    for (int d = 0; d < Ddim; ++d)
        s += e1[i * Ddim + d] * e2[j * Ddim + d]
           - e2[i * Ddim + d] * e1[j * Ddim + d];
    float t = 1.f - 2.f * frcp(fexp(2.f * s) + 1.f);
    float v = fmaxf(t, 0.f);
    if (i == j) v += 1.f;
    Sbf[idx] = f2bf(v);
}

// ---------------------------------------------------------------- row softmax (bf16 out)
__global__ __launch_bounds__(256) void k_softmax_rows(
    const float* __restrict__ In, short* __restrict__ Out)
{
    int row = blockIdx.x;
    const float* r = In + (size_t)row * Ndim;
    short* o = Out + (size_t)row * Ndim;
    __shared__ float red[256];
    int tid = threadIdx.x;
    float vals[4];
    float lmax = -INFINITY;
#pragma unroll
    for (int i = 0; i < 4; ++i) { vals[i] = r[tid + 256 * i]; lmax = fmaxf(lmax, vals[i]); }
    red[tid] = lmax; __syncthreads();
    for (int s = 128; s > 0; s >>= 1) {
        if (tid < s) red[tid] = fmaxf(red[tid], red[tid + s]);
        __syncthreads();
    }
    float m = red[0]; __syncthreads();
    float lsum = 0.f;
#pragma unroll
    for (int i = 0; i < 4; ++i) { vals[i] = fexp(vals[i] - m); lsum += vals[i]; }
    red[tid] = lsum; __syncthreads();
    for (int s = 128; s > 0; s >>= 1) {
        if (tid < s) red[tid] += red[tid + s];
        __syncthreads();
    }
    float inv = frcp(red[0]);
#pragma unroll
    for (int i = 0; i < 4; ++i) o[tid + 256 * i] = f2bf(vals[i] * inv);
}

// ---------------------------------------------------------------- x -> xbf + xT bf16
__global__ __launch_bounds__(256) void k_cvt_x(
    const float* __restrict__ x, short* __restrict__ xbf, short* __restrict__ xT)
{
    __shared__ float Lt[64][65];
    int bt = blockIdx.y, n0 = blockIdx.x * 64;
    const float* src = x + (size_t)bt * 65536 + (size_t)n0 * 64;
    int tid = threadIdx.x;
#pragma unroll
    for (int p = 0; p < 4; ++p) {
        int idx = p * 256 + tid;
        int r = idx >> 4, c4 = idx & 15;
        float4 v = *(const float4*)&src[r * 64 + c4 * 4];
        short4 s4 = make_short4(f2bf(v.x), f2bf(v.y), f2bf(v.z), f2bf(v.w));
        *(short4*)&xbf[(size_t)bt * 65536 + (size_t)(n0 + r) * 64 + c4 * 4] = s4;
        Lt[r][c4 * 4 + 0] = v.x; Lt[r][c4 * 4 + 1] = v.y;
        Lt[r][c4 * 4 + 2] = v.z; Lt[r][c4 * 4 + 3] = v.w;
    }
    __syncthreads();
#pragma unroll
    for (int p = 0; p < 4; ++p) {
        int idx = p * 256 + tid;
        int c = idx >> 4, k4 = idx & 15;
        short4 s4 = make_short4(f2bf(Lt[k4 * 4 + 0][c]), f2bf(Lt[k4 * 4 + 1][c]),
                                f2bf(Lt[k4 * 4 + 2][c]), f2bf(Lt[k4 * 4 + 3][c]));
        *(short4*)&xT[(size_t)bt * 65536 + (size_t)c * 1024 + n0 + k4 * 4] = s4;
    }
}

// ---------------------------------------------------------------- wpool -> wpT bf16 (4096x1024)
__global__ __launch_bounds__(256) void k_cvt_wp(
    const float* __restrict__ wp, short* __restrict__ wpT)
{
    __shared__ float Lt[64][65];
    int k0 = blockIdx.y * 64, j0 = blockIdx.x * 64;
    int tid = threadIdx.x;
#pragma unroll
    for (int p = 0; p < 4; ++p) {
        int idx = p * 256 + tid;
        int r = idx >> 4, c4 = idx & 15;
        float4 v = *(const float4*)&wp[(size_t)(k0 + r) * IOdim + j0 + c4 * 4];
        Lt[r][c4 * 4 + 0] = v.x; Lt[r][c4 * 4 + 1] = v.y;
        Lt[r][c4 * 4 + 2] = v.z; Lt[r][c4 * 4 + 3] = v.w;
    }
    __syncthreads();
#pragma unroll
    for (int p = 0; p < 4; ++p) {
        int idx = p * 256 + tid;
        int c = idx >> 4, k4 = idx & 15;
        short4 s4 = make_short4(f2bf(Lt[k4 * 4 + 0][c]), f2bf(Lt[k4 * 4 + 1][c]),
                                f2bf(Lt[k4 * 4 + 2][c]), f2bf(Lt[k4 * 4 + 3][c]));
        *(short4*)&wpT[(size_t)(j0 + c) * 1024 + k0 + k4 * 4] = s4;
    }
}

// ---------------------------------------------------------------- bpool (1024x64 f32) -> bpT (64x1024 bf16)
__global__ __launch_bounds__(256) void k_cvt_bp(
    const float* __restrict__ bp, short* __restrict__ bpT)
{
    __shared__ float Lt[64][65];
    int k0 = blockIdx.x * 64;
    int tid = threadIdx.x;
#pragma unroll
    for (int p = 0; p < 4; ++p) {
        int idx = p * 256 + tid;
        int r = idx >> 4, c4 = idx & 15;
        float4 v = *(const float4*)&bp[(size_t)(k0 + r) * 64 + c4 * 4];
        Lt[r][c4 * 4 + 0] = v.x; Lt[r][c4 * 4 + 1] = v.y;
        Lt[r][c4 * 4 + 2] = v.z; Lt[r][c4 * 4 + 3] = v.w;
    }
    __syncthreads();
#pragma unroll
    for (int p = 0; p < 4; ++p) {
        int idx = p * 256 + tid;
        int c = idx >> 4, k4 = idx & 15;       // c = o-row, k4 = k-chunk
        short4 s4 = make_short4(f2bf(Lt[k4 * 4 + 0][c]), f2bf(Lt[k4 * 4 + 1][c]),
                                f2bf(Lt[k4 * 4 + 2][c]), f2bf(Lt[k4 * 4 + 3][c]));
        *(short4*)&bpT[(size_t)c * 1024 + k0 + k4 * 4] = s4;
    }
}

// ---------------------------------------------------------------- m97-style bf16 GEMM, C = A @ B^T
template<int MODE>
__global__ __launch_bounds__(256) void k_gemm_bt(
    const short* __restrict__ A, const short* __restrict__ Bm,
    float* __restrict__ Cf, short* __restrict__ Cb,
    const float* __restrict__ gamma_p)
{
    __shared__ short At[128 * 64];
    __shared__ short Bt[128 * 64];
    const int tid = threadIdx.x;
    const int w = tid >> 6, l = tid & 63;
    const int l15 = l & 15, q = l >> 4;
    const int n0 = blockIdx.x * 128, j0 = blockIdx.y * 128;
    const int wr = (w & 1) * 64, wc = (w >> 1) * 64;
    const int lrow = l >> 3, lc8 = l & 7;

    f32x4 acc[4][4];
#pragma unroll
    for (int i = 0; i < 4; ++i)
#pragma unroll
        for (int j = 0; j < 4; ++j) acc[i][j] = (f32x4)0.f;

    for (int k0 = 0; k0 < 1024; k0 += 64) {
        __syncthreads();
#pragma unroll
        for (int p = 0; p < 4; ++p) {
            int r = p * 32 + w * 8 + lrow;
            int sc = lc8 ^ (r & 7);
            load_lds16(A + (size_t)(n0 + r) * 1024 + k0 + sc * 8,
                       &At[(p * 32 + w * 8) * 64]);
            load_lds16(Bm + (size_t)(j0 + r) * 1024 + k0 + sc * 8,
                       &Bt[(p * 32 + w * 8) * 64]);
        }
        __syncthreads();
#pragma unroll
        for (int ks = 0; ks < 2; ++ks) {
            bf16x8 af[4], bf[4];
#pragma unroll
            for (int rt = 0; rt < 4; ++rt) {
                int row = wr + rt * 16 + l15;
                int pos = (ks * 4 + q) ^ (row & 7);
                af[rt] = *(const bf16x8*)&At[row * 64 + pos * 8];
            }
#pragma unroll
            for (int ct = 0; ct < 4; ++ct) {
                int row = wc + ct * 16 + l15;
                int pos = (ks * 4 + q) ^ (row & 7);
                bf[ct] = *(const bf16x8*)&Bt[row * 64 + pos * 8];
            }
#pragma unroll
            for (int rt = 0; rt < 4; ++rt)
#pragma unroll
                for (int ct = 0; ct < 4; ++ct)
                    acc[rt][ct] = __builtin_amdgcn_mfma_f32_16x16x32_bf16(
                        af[rt], bf[ct], acc[rt][ct], 0, 0, 0);
        }
    }

    float gmm = (MODE == 0) ? gamma_p[0] : 0.f;
#pragma unroll
    for (int rt = 0; rt < 4; ++rt) {
        int nr = n0 + wr + rt * 16 + q * 4;
#pragma unroll
        for (int ct = 0; ct < 4; ++ct) {
            int j = j0 + wc + ct * 16 + l15;
#pragma unroll
            for (int r = 0; r < 4; ++r) {
                float v = acc[rt][ct][r];
                int n = nr + r;
                if (MODE == 1) {
                    Cb[(size_t)n * IOdim + j] = f2bf(v);
                } else if (n < 1024) {
                    int bt = j >> 6, c = j & 63;
                    Cf[(size_t)bt * 65536 + (size_t)n * 64 + c] = gmm * fmaxf(v, 0.f);
                } else {
                    Cb[(size_t)(n - 1024) * Jdim + j] = f2bf(v);
                }
            }
        }
    }
}

// ---------------------------------------------------------------- SA phase 1: L = logsumexp_t S (f16 out)
// S[t,n,m] = x[t,n].x[t,m] is SYMMETRIC in (n,m) -> L is symmetric. Compute only the
// upper-triangle tile pairs (tn <= tm): 136 pairs x 8 batches = 1088 blocks; write
// L[n,m] vectorized + L[m,n] scalar-transposed for off-diagonal blocks. Halves z's
// X-read traffic (~400 -> ~220 MB) and its MFMA count. Geometry/staging otherwise
// identical to the r10-proven 64x64 kernel. b = blockIdx % 8 -> XCD-local.
__global__ __launch_bounds__(256, 4) void k_sa_z(
    const short* __restrict__ xbf, short* __restrict__ Lh)
{
    __shared__ short Xn[64 * 64];
    __shared__ short Xm[64 * 64];

    int id = blockIdx.x;
    int b = id & 7;
    int r = id >> 3;                     // 0..135 (upper-tri pair index)
    int tn = 0, rr = r;
    while (rr >= 16 - tn) { rr -= 16 - tn; ++tn; }
    int tm = tn + rr;
    int tid = threadIdx.x;
    int w = tid >> 6, l = tid & 63;
    int l15 = l & 15, q = l >> 4;
    int lrow = l >> 3, lc8 = l & 7;
    int n0 = tn * 64, m0 = tm * 64;
    int wn = (w & 1) * 32, wm = (w >> 1) * 32;

    const short* Xb = xbf + (size_t)b * Tdim * Ndim * Cdim;
    short* Lb = Lh + ((size_t)b << 20);

    f32x4 M[2][2], Z[2][2];
#pragma unroll
    for (int nh = 0; nh < 2; ++nh)
#pragma unroll
        for (int mh = 0; mh < 2; ++mh) { M[nh][mh] = (f32x4)(-INFINITY); Z[nh][mh] = (f32x4)0.f; }

    for (int t = 0; t < Tdim; ++t) {
        const short* xt = Xb + (size_t)t * (Ndim * Cdim);
        __syncthreads();                 // protect prev-iter LDS reads
#pragma unroll
        for (int p = 0; p < 2; ++p) {
            int rw = p * 32 + w * 8 + lrow;
            int sc = lc8 ^ (rw & 7);
            load_lds16(xt + (size_t)(n0 + rw) * 64 + sc * 8, &Xn[(p * 32 + w * 8) * 64]);
            load_lds16(xt + (size_t)(m0 + rw) * 64 + sc * 8, &Xm[(p * 32 + w * 8) * 64]);
        }
        __syncthreads();

        f32x4 sacc[2][2];
        sacc[0][0] = (f32x4)0.f; sacc[0][1] = (f32x4)0.f;
        sacc[1][0] = (f32x4)0.f; sacc[1][1] = (f32x4)0.f;
#pragma unroll
        for (int ch = 0; ch < 2; ++ch) {
            bf16x8 qb[2], af[2];
#pragma unroll
            for (int nh = 0; nh < 2; ++nh) {
                int row = wn + nh * 16 + l15;
                int pos = (ch * 4 + q) ^ (row & 7);
                qb[nh] = *(const bf16x8*)&Xn[row * 64 + pos * 8];
            }
#pragma unroll
            for (int mh = 0; mh < 2; ++mh) {
                int row = wm + mh * 16 + l15;
                int pos = (ch * 4 + q) ^ (row & 7);
                af[mh] = *(const bf16x8*)&Xm[row * 64 + pos * 8];
            }
#pragma unroll
            for (int nh = 0; nh < 2; ++nh)
#pragma unroll
                for (int mh = 0; mh < 2; ++mh)
                    sacc[nh][mh] = __builtin_amdgcn_mfma_f32_16x16x32_bf16(
                        af[mh], qb[nh], sacc[nh][mh], 0, 0, 0);
        }
        // online LSE update
#pragma unroll
        for (int nh = 0; nh < 2; ++nh)
#pragma unroll
            for (int mh = 0; mh < 2; ++mh)
#pragma unroll
                for (int i = 0; i < 4; ++i) {
                    float s  = sacc[nh][mh][i];
                    float mo = M[nh][mh][i];
                    float mn = fmaxf(mo, s);
                    Z[nh][mh][i] = Z[nh][mh][i] * fexp(mo - mn) + fexp(s - mn);
                    M[nh][mh][i] = mn;
                }
    }
#pragma unroll
    for (int nh = 0; nh < 2; ++nh)
#pragma unroll
        for (int mh = 0; mh < 2; ++mh) {
            f16x4 ev;
#pragma unroll
            for (int i = 0; i < 4; ++i)
                ev[i] = (_Float16)(M[nh][mh][i] + flog(Z[nh][mh][i]));
            int nn = n0 + wn + nh * 16 + l15;
            int mm = m0 + wm + mh * 16 + q * 4;
            *(f16x4*)&Lb[(size_t)nn * 1024 + mm] = ev;
            if (tn != tm) {
                // transposed write (L symmetric)
#pragma unroll
                for (int i = 0; i < 4; ++i)
                    Lb[(size_t)(mm + i) * 1024 + nn] = ((short*)&ev)[i];
            }
        }
}

// ---------------------------------------------------------------- SA phase 2: out += beta*relu(PV)
// r14 falsifier: barrier count null; budget shows conflicts ~20% of time (8.65M).
// This round: replace padded-stride LDS layouts with the gemm-proven XOR-swizzle
// (stride 64, granule pos = chunk ^ (row&7), mirrored write/read) for Xm, XTl, Pl.
// Structure (MT64, single-barrier double-buffer, 768 blocks) unchanged.
__global__ __launch_bounds__(256, 3) void k_sa_pv(
    const short* __restrict__ xbf, const short* __restrict__ xT,
    const short* __restrict__ Lh, float* __restrict__ Out,
    const float* __restrict__ beta_p)
{
    __shared__ short Xm[2][64 * 64];     // [buf][m][c], XOR-swizzled granules
    __shared__ short XTl[2][64 * 64];    // [buf][c][m], XOR-swizzled granules
    __shared__ short Pl[4][16 * 64];     // [wave][n][m], XOR-swizzled granules

    int id = blockIdx.x;
    int b = id & 7;
    int r = id >> 3;                     // 0..95
    int nt = r & 7, t = r >> 3;
    int tid = threadIdx.x;
    int w = tid >> 6, l = tid & 63;
    int l15 = l & 15, q = l >> 4;
    int n0 = nt * 128 + w * 32;

    const short* Xb  = xbf + ((size_t)b * Tdim + t) * (Ndim * Cdim);
    const short* XTb = xT  + ((size_t)b * Tdim + t) * (Ndim * Cdim);
    const short* Lb  = Lh + ((size_t)b << 20);

    int srow = tid >> 2, sc4 = tid & 3;  // staging: 64 rows x (2 passes x 4) 16B granules

    // Q B-fragments cached across the m sweep
    bf16x8 qf[2][2];
#pragma unroll
    for (int nh = 0; nh < 2; ++nh)
#pragma unroll
        for (int ch = 0; ch < 2; ++ch)
            qf[nh][ch] = *(const bf16x8*)&Xb[(n0 + nh * 16 + l15) * 64 + ch * 32 + q * 8];

    f32x4 oacc[2][4];
#pragma unroll
    for (int nh = 0; nh < 2; ++nh)
#pragma unroll
        for (int ct = 0; ct < 4; ++ct) oacc[nh][ct] = (f32x4)0.f;

    // preload tile 0 into regs
    bf16x8 v[2], v2[2];
#pragma unroll
    for (int p = 0; p < 2; ++p) {
        v[p]  = *(const bf16x8*)&Xb[(size_t)srow * 64 + (sc4 + 4 * p) * 8];
        v2[p] = *(const bf16x8*)&XTb[(size_t)srow * 1024 + (sc4 + 4 * p) * 8];
    }

    for (int mi = 0; mi < 16; ++mi) {
        int cur = mi & 1;
        int m0 = mi * 64;
        // ---- write tile mi into buf[cur], XOR-swizzled granules
#pragma unroll
        for (int p = 0; p < 2; ++p) {
            int g = sc4 + 4 * p;
            int pos = g ^ (srow & 7);
            *(bf16x8*)&Xm[cur][srow * 64 + pos * 8]  = v[p];
            *(bf16x8*)&XTl[cur][srow * 64 + pos * 8] = v2[p];
        }
        // ---- prefetch tile mi+1 (lands during barrier + compute)
        int m0n = (mi < 15) ? m0 + 64 : m0;
#pragma unroll
        for (int p = 0; p < 2; ++p) {
            v[p]  = *(const bf16x8*)&Xb[(size_t)(m0n + srow) * 64 + (sc4 + 4 * p) * 8];
            v2[p] = *(const bf16x8*)&XTb[(size_t)srow * 1024 + m0n + (sc4 + 4 * p) * 8];
        }
        // ---- e loads for this iter (global, land under scores compute)
        f16x4 e[2][4];
#pragma unroll
        for (int nh = 0; nh < 2; ++nh)
#pragma unroll
            for (int mh = 0; mh < 4; ++mh)
                e[nh][mh] = *(const f16x4*)&Lb[(size_t)(n0 + nh * 16 + l15) * 1024
                                               + m0 + mh * 16 + q * 4];
        __syncthreads();                 // single barrier per iter

        // ---- scores from Xm[cur] (S[n32][m64])
        f32x4 sacc[2][4];
#pragma unroll
        for (int nh = 0; nh < 2; ++nh)
#pragma unroll
            for (int mh = 0; mh < 4; ++mh) sacc[nh][mh] = (f32x4)0.f;
#pragma unroll
        for (int ch = 0; ch < 2; ++ch) {
#pragma unroll
            for (int mh = 0; mh < 4; ++mh) {
                int row = mh * 16 + l15;
                int pos = (ch * 4 + q) ^ (row & 7);
                bf16x8 af = *(const bf16x8*)&Xm[cur][row * 64 + pos * 8];
                sacc[0][mh] = __builtin_amdgcn_mfma_f32_16x16x32_bf16(
                    af, qf[0][ch], sacc[0][mh], 0, 0, 0);
                sacc[1][mh] = __builtin_amdgcn_mfma_f32_16x16x32_bf16(
                    af, qf[1][ch], sacc[1][mh], 0, 0, 0);
            }
        }
        // ---- per nh: p = exp(S-L) pack -> wave-private Pl (swizzled) -> PV
#pragma unroll
        for (int nh = 0; nh < 2; ++nh) {
#pragma unroll
            for (int mh = 0; mh < 4; ++mh) {
                f32x4 p = sacc[nh][mh];
                f16x4 ee = e[nh][mh];
                unsigned u0 = (unsigned)(unsigned short)f2bf(fexp(p[0] - (float)ee[0]))
                            | ((unsigned)(unsigned short)f2bf(fexp(p[1] - (float)ee[1])) << 16);
                unsigned u1 = (unsigned)(unsigned short)f2bf(fexp(p[2] - (float)ee[2]))
                            | ((unsigned)(unsigned short)f2bf(fexp(p[3] - (float)ee[3])) << 16);
                // granule of m = mh*16 + q*4 is g = mh*2 + (q>>1); in-granule ofs (q&1)*4
                int g = mh * 2 + (q >> 1);
                int pos = g ^ (l15 & 7);
                *(uint2*)&Pl[w][l15 * 64 + pos * 8 + (q & 1) * 4] = make_uint2(u0, u1);
            }
#pragma unroll
            for (int ks = 0; ks < 2; ++ks) {
                int gr = ks * 4 + q;
                int pos = gr ^ (l15 & 7);
                bf16x8 pf = *(const bf16x8*)&Pl[w][l15 * 64 + pos * 8];
#pragma unroll
                for (int ct = 0; ct < 4; ++ct) {
                    int row = ct * 16 + l15;
                    int bp = (ks * 4 + q) ^ (row & 7);
                    bf16x8 bfr = *(const bf16x8*)&XTl[cur][row * 64 + bp * 8];
                    oacc[nh][ct] = __builtin_amdgcn_mfma_f32_16x16x32_bf16(
                        pf, bfr, oacc[nh][ct], 0, 0, 0);
                }
            }
        }
    }

    float beta = beta_p[0];
#pragma unroll
    for (int nh = 0; nh < 2; ++nh)
#pragma unroll
        for (int ct = 0; ct < 4; ++ct)
#pragma unroll
            for (int r2 = 0; r2 < 4; ++r2) {
                size_t idx = (((size_t)b * Tdim + t) * Ndim + n0 + nh * 16 + q * 4 + r2) * Cdim
                           + ct * 16 + l15;
                Out[idx] += beta * fmaxf(oacc[nh][ct][r2], 0.f);
            }
}

// ---------------------------------------------------------------- bias = S @ bpool via MFMA
__global__ __launch_bounds__(256) void k_bias(
    const short* __restrict__ Sbf, const short* __restrict__ bpT,
    float* __restrict__ bias)
{
    int tid = threadIdx.x;
    int w = tid >> 6, l = tid & 63;
    int l15 = l & 15, q = l >> 4;
    int nr = blockIdx.x * 64 + w * 16;

    f32x4 acc[4];
#pragma unroll
    for (int ct = 0; ct < 4; ++ct) acc[ct] = (f32x4)0.f;

    for (int k0 = 0; k0 < 1024; k0 += 32) {
        bf16x8 af = *(const bf16x8*)&Sbf[(size_t)(nr + l15) * 1024 + k0 + q * 8];
#pragma unroll
        for (int ct = 0; ct < 4; ++ct) {
            bf16x8 bf = *(const bf16x8*)&bpT[(size_t)(ct * 16 + l15) * 1024 + k0 + q * 8];
            acc[ct] = __builtin_amdgcn_mfma_f32_16x16x32_bf16(af, bf, acc[ct], 0, 0, 0);
        }
    }
#pragma unroll
    for (int ct = 0; ct < 4; ++ct)
#pragma unroll
        for (int r = 0; r < 4; ++r)
            bias[(size_t)(nr + q * 4 + r) * 64 + ct * 16 + l15] = acc[ct][r];
}

// ---------------------------------------------------------------- gconv via MFMA (6 waves)
__global__ __launch_bounds__(384) void k_gconv(
    const short* __restrict__ xgT, const short* __restrict__ Wb,
    const float* __restrict__ bias, float* __restrict__ Out,
    const float* __restrict__ alpha_p)
{
    __shared__ short Wl[64 * 64];
    int n = blockIdx.x;
    int tid = threadIdx.x;
    for (int f = tid; f < 512; f += 384) {
        int k = f >> 3, j = f & 7;
        *(bf16x8*)&Wl[k * 64 + (j ^ ((k >> 3) & 7)) * 8] =
            *(const bf16x8*)&Wb[(size_t)n * IOdim + f * 8];
    }
    __syncthreads();
    int w = tid / 64, l = tid & 63, l15 = l & 15, q = l >> 4;
    f32x4 acc[4];
#pragma unroll
    for (int ct = 0; ct < 4; ++ct) acc[ct] = (f32x4)0.f;
    const short* xr = xgT + (size_t)n * Jdim + (size_t)(w * 16 + l15) * 64;
#pragma unroll
    for (int ks = 0; ks < 2; ++ks) {
        bf16x8 a = *(const bf16x8*)&xr[ks * 32 + q * 8];
        int kb = ks * 32 + q * 8;
        int msk = (kb >> 3) & 7;
#pragma unroll
        for (int ct = 0; ct < 4; ++ct) {
            bf16x8 bfr;
#pragma unroll
            for (int e = 0; e < 8; ++e) {
                int o = ct * 16 + l15;
                bfr[e] = Wl[(kb + e) * 64 + (((o >> 3) ^ msk) * 8) + (o & 7)];
            }
            acc[ct] = __builtin_amdgcn_mfma_f32_16x16x32_bf16(a, bfr, acc[ct], 0, 0, 0);
        }
    }
    float alpha = alpha_p[0];
#pragma unroll
    for (int ct = 0; ct < 4; ++ct) {
        int o = ct * 16 + l15;
        float bo = bias[(size_t)n * 64 + o];
#pragma unroll
        for (int r = 0; r < 4; ++r) {
            int bt = w * 16 + q * 4 + r;
            size_t idx = (size_t)bt * 65536 + (size_t)n * 64 + o;
            Out[idx] += alpha * fmaxf(acc[ct][r] + bo, 0.f);
        }
    }
}

// ---------------------------------------------------------------- launch
extern "C" void kernel_launch(void* const* d_in, const int* in_sizes, int n_in,
                              void* d_out, int out_size, void* d_ws, size_t ws_size,
                              hipStream_t stream)
{
    const float* x     = (const float*)d_in[0];
    const float* e1    = (const float*)d_in[1];
    const float* e2    = (const float*)d_in[2];
    const float* Asym  = (const float*)d_in[3];
    const float* wpool = (const float*)d_in[4];
    const float* bpool = (const float*)d_in[5];
    const float* alpha = (const float*)d_in[6];
    const float* beta  = (const float*)d_in[7];
    const float* gamma = (const float*)d_in[8];
    float* out = (float*)d_out;

    short* ASbf = (short*)d_ws;                       // 2048x1024   (4 MB)
    short* xbf  = ASbf + 2048 * 1024;                 // 12.6 MB
    short* xT   = xbf  + 6291456;                     // 12.6 MB
    short* wpT  = xT   + 6291456;                     // 8.4 MB
    short* Wbf  = wpT  + 4194304;                     // 8.4 MB
    short* xgT  = Wbf  + 4194304;                     // 12.6 MB
    float* bias = (float*)(xgT + 6291456);            // 256 KB
    short* Lh   = (short*)(bias + 65536);             // 16.8 MB (logsumexp_t, f16)
    short* bpT  = Lh + 8388608;                       // 128 KB (bpool^T bf16)

    k_supports<<<4096, 256, 0, stream>>>(e1, e2, ASbf + 1024 * 1024);
    k_softmax_rows<<<1024, 256, 0, stream>>>(Asym, ASbf);
    k_cvt_x<<<dim3(16, 96), 256, 0, stream>>>(x, xbf, xT);
    k_cvt_wp<<<dim3(64, 16), 256, 0, stream>>>(wpool, wpT);
    k_cvt_bp<<<16, 256, 0, stream>>>(bpool, bpT);
    // SA phase 1: symmetric upper-triangle tiles (L[n,m]=L[m,n]), f16 out
    k_sa_z<<<1088, 256, 0, stream>>>(xbf, Lh);
    // stacked: rows 0..1023 -> out = gamma*relu(A@x); rows 1024..2047 -> xgT = S@x
    k_gemm_bt<0><<<dim3(16, 48), 256, 0, stream>>>(ASbf, xT, out, xgT, gamma);
    // Wbf = S @ wpool
    k_gemm_bt<1><<<dim3(8, 32), 256, 0, stream>>>(ASbf + 1024 * 1024, wpT, nullptr, Wbf, nullptr);
    // bias = S @ bpool (MFMA, L2-resident)
    k_bias<<<16, 256, 0, stream>>>(ASbf + 1024 * 1024, bpT, bias);
    // SA phase 2: out += beta*relu(PV); MT64 dbuf + XOR-swizzled LDS
    k_sa_pv<<<768, 256, 0, stream>>>(xbf, xT, Lh, out, beta);
    // out += alpha * relu(xgT @ W[n] + bias[n])
    k_gconv<<<1024, 384, 0, stream>>>(xgT, Wbf, bias, out, alpha);
}

// Round 16
// 303.907 us; speedup vs baseline: 1.0607x; 1.0264x over previous
//
#include <hip/hip_runtime.h>
#include <math.h>

#define Bdim 8
#define Tdim 12
#define BT   96
#define Ndim 1024
#define Cdim 64
#define Ddim 10
#define Jdim 6144      // BT*C
#define IOdim 4096     // C*C
#define LOG2E 1.44269504088896f

typedef __attribute__((ext_vector_type(4))) float f32x4;
typedef __attribute__((ext_vector_type(8))) short bf16x8;
typedef __attribute__((ext_vector_type(4))) _Float16 f16x4;

__device__ inline short f2bf(float f) {
    union { float f; unsigned u; } v; v.f = f;
    return (short)((v.u + 0x8000u) >> 16);
}
__device__ inline float bf2f(short s) {
    union { float f; unsigned u; } v; v.u = ((unsigned)(unsigned short)s) << 16;
    return v.f;
}
__device__ inline void load_lds16(const void* g, void* l) {
    __builtin_amdgcn_global_load_lds(
        (const __attribute__((address_space(1))) unsigned int*)g,
        (__attribute__((address_space(3))) unsigned int*)l, 16, 0, 0);
}
// fast exp / rcp / log2 (native v_exp_f32 / v_rcp_f32 / v_log_f32)
__device__ inline float fexp(float x) { return __expf(x); }
__device__ inline float frcp(float x) { return __builtin_amdgcn_rcpf(x); }
// pack two f32 -> one u32 of 2 bf16 (guide T12 recipe; no builtin on gfx950)
__device__ inline unsigned pk_bf16(float lo, float hi) {
    unsigned r;
    asm("v_cvt_pk_bf16_f32 %0, %1, %2" : "=v"(r) : "v"(lo), "v"(hi));
    return r;
}

// ---------------------------------------------------------------- fused prep:
// blocks 0..4095: supports (bf16); 4096..5119: row-softmax of Asym; 5120..5135: bpT
__global__ __launch_bounds__(256) void k_prep(
    const float* __restrict__ e1, const float* __restrict__ e2,
    short* __restrict__ Sup,
    const float* __restrict__ Asym, short* __restrict__ SMout,
    const float* __restrict__ bp, short* __restrict__ bpT)
{
    __shared__ float red[256];
    __shared__ float Lt[64][65];
    int blk = blockIdx.x;
    int tid = threadIdx.x;
    if (blk < 4096) {
        // ---- supports: relu(tanh(E1E2^T - E2E1^T)) + I
        int idx = blk * 256 + tid;
        int i = idx >> 10, j = idx & 1023;
        float s = 0.f;
#pragma unroll
        for (int d = 0; d < Ddim; ++d)
            s += e1[i * Ddim + d] * e2[j * Ddim + d]
               - e2[i * Ddim + d] * e1[j * Ddim + d];
        float t = 1.f - 2.f * frcp(fexp(2.f * s) + 1.f);
        float v = fmaxf(t, 0.f);
        if (i == j) v += 1.f;
        Sup[idx] = f2bf(v);
    } else if (blk < 5120) {
        // ---- row softmax of Asym (bf16 out)
        int row = blk - 4096;
        const float* r = Asym + (size_t)row * Ndim;
        short* o = SMout + (size_t)row * Ndim;
        float vals[4];
        float lmax = -INFINITY;
#pragma unroll
        for (int i = 0; i < 4; ++i) { vals[i] = r[tid + 256 * i]; lmax = fmaxf(lmax, vals[i]); }
        red[tid] = lmax; __syncthreads();
        for (int s = 128; s > 0; s >>= 1) {
            if (tid < s) red[tid] = fmaxf(red[tid], red[tid + s]);
            __syncthreads();
        }
        float m = red[0]; __syncthreads();
        float lsum = 0.f;
#pragma unroll
        for (int i = 0; i < 4; ++i) { vals[i] = fexp(vals[i] - m); lsum += vals[i]; }
        red[tid] = lsum; __syncthreads();
        for (int s = 128; s > 0; s >>= 1) {
            if (tid < s) red[tid] += red[tid + s];
            __syncthreads();
        }
        float inv = frcp(red[0]);
#pragma unroll
        for (int i = 0; i < 4; ++i) o[tid + 256 * i] = f2bf(vals[i] * inv);
    } else {
        // ---- bpool (1024x64 f32) -> bpT (64x1024 bf16)
        int k0 = (blk - 5120) * 64;
#pragma unroll
        for (int p = 0; p < 4; ++p) {
            int idx = p * 256 + tid;
            int r = idx >> 4, c4 = idx & 15;
            float4 v = *(const float4*)&bp[(size_t)(k0 + r) * 64 + c4 * 4];
            Lt[r][c4 * 4 + 0] = v.x; Lt[r][c4 * 4 + 1] = v.y;
            Lt[r][c4 * 4 + 2] = v.z; Lt[r][c4 * 4 + 3] = v.w;
        }
        __syncthreads();
#pragma unroll
        for (int p = 0; p < 4; ++p) {
            int idx = p * 256 + tid;
            int c = idx >> 4, k4 = idx & 15;
            short4 s4 = make_short4(f2bf(Lt[k4 * 4 + 0][c]), f2bf(Lt[k4 * 4 + 1][c]),
                                    f2bf(Lt[k4 * 4 + 2][c]), f2bf(Lt[k4 * 4 + 3][c]));
            *(short4*)&bpT[(size_t)c * 1024 + k0 + k4 * 4] = s4;
        }
    }
}

// ---------------------------------------------------------------- fused cvt:
// blocks 0..1535: x -> xbf + xT; 1536..2559: wpool -> wpT
__global__ __launch_bounds__(256) void k_cvt2(
    const float* __restrict__ x, short* __restrict__ xbf, short* __restrict__ xT,
    const float* __restrict__ wp, short* __restrict__ wpT)
{
    __shared__ float Lt[64][65];
    int blk = blockIdx.x;
    int tid = threadIdx.x;
    if (blk < 1536) {
        int bt = blk >> 4, n0 = (blk & 15) * 64;
        const float* src = x + (size_t)bt * 65536 + (size_t)n0 * 64;
#pragma unroll
        for (int p = 0; p < 4; ++p) {
            int idx = p * 256 + tid;
            int r = idx >> 4, c4 = idx & 15;
            float4 v = *(const float4*)&src[r * 64 + c4 * 4];
            short4 s4 = make_short4(f2bf(v.x), f2bf(v.y), f2bf(v.z), f2bf(v.w));
            *(short4*)&xbf[(size_t)bt * 65536 + (size_t)(n0 + r) * 64 + c4 * 4] = s4;
            Lt[r][c4 * 4 + 0] = v.x; Lt[r][c4 * 4 + 1] = v.y;
            Lt[r][c4 * 4 + 2] = v.z; Lt[r][c4 * 4 + 3] = v.w;
        }
        __syncthreads();
#pragma unroll
        for (int p = 0; p < 4; ++p) {
            int idx = p * 256 + tid;
            int c = idx >> 4, k4 = idx & 15;
            short4 s4 = make_short4(f2bf(Lt[k4 * 4 + 0][c]), f2bf(Lt[k4 * 4 + 1][c]),
                                    f2bf(Lt[k4 * 4 + 2][c]), f2bf(Lt[k4 * 4 + 3][c]));
            *(short4*)&xT[(size_t)bt * 65536 + (size_t)c * 1024 + n0 + k4 * 4] = s4;
        }
    } else {
        int b2 = blk - 1536;
        int k0 = (b2 >> 6) * 64, j0 = (b2 & 63) * 64;
#pragma unroll
        for (int p = 0; p < 4; ++p) {
            int idx = p * 256 + tid;
            int r = idx >> 4, c4 = idx & 15;
            float4 v = *(const float4*)&wp[(size_t)(k0 + r) * IOdim + j0 + c4 * 4];
            Lt[r][c4 * 4 + 0] = v.x; Lt[r][c4 * 4 + 1] = v.y;
            Lt[r][c4 * 4 + 2] = v.z; Lt[r][c4 * 4 + 3] = v.w;
        }
        __syncthreads();
#pragma unroll
        for (int p = 0; p < 4; ++p) {
            int idx = p * 256 + tid;
            int c = idx >> 4, k4 = idx & 15;
            short4 s4 = make_short4(f2bf(Lt[k4 * 4 + 0][c]), f2bf(Lt[k4 * 4 + 1][c]),
                                    f2bf(Lt[k4 * 4 + 2][c]), f2bf(Lt[k4 * 4 + 3][c]));
            *(short4*)&wpT[(size_t)(j0 + c) * 1024 + k0 + k4 * 4] = s4;
        }
    }
}

// ---------------------------------------------------------------- m97-style bf16 GEMM, C = A @ B^T
// Flat grid + bijective XCD swizzle (T1): nwg%8==0 for both modes.
template<int MODE>
__global__ __launch_bounds__(256) void k_gemm_bt(
    const short* __restrict__ A, const short* __restrict__ Bm,
    float* __restrict__ Cf, short* __restrict__ Cb,
    const float* __restrict__ gamma_p)
{
    __shared__ short At[128 * 64];
    __shared__ short Bt[128 * 64];
    const int tid = threadIdx.x;
    const int w = tid >> 6, l = tid & 63;
    const int l15 = l & 15, q = l >> 4;
    const int nwg  = (MODE == 0) ? 768 : 256;
    const int nbx  = (MODE == 0) ? 16 : 8;
    int raw = blockIdx.x;
    int sw  = (raw & 7) * (nwg >> 3) + (raw >> 3);   // XCD-contiguous chunks
    const int n0 = (sw % nbx) * 128, j0 = (sw / nbx) * 128;
    const int wr = (w & 1) * 64, wc = (w >> 1) * 64;
    const int lrow = l >> 3, lc8 = l & 7;

    f32x4 acc[4][4];
#pragma unroll
    for (int i = 0; i < 4; ++i)
#pragma unroll
        for (int j = 0; j < 4; ++j) acc[i][j] = (f32x4)0.f;

    for (int k0 = 0; k0 < 1024; k0 += 64) {
        __syncthreads();
#pragma unroll
        for (int p = 0; p < 4; ++p) {
            int r = p * 32 + w * 8 + lrow;
            int sc = lc8 ^ (r & 7);
            load_lds16(A + (size_t)(n0 + r) * 1024 + k0 + sc * 8,
                       &At[(p * 32 + w * 8) * 64]);
            load_lds16(Bm + (size_t)(j0 + r) * 1024 + k0 + sc * 8,
                       &Bt[(p * 32 + w * 8) * 64]);
        }
        __syncthreads();
#pragma unroll
        for (int ks = 0; ks < 2; ++ks) {
            bf16x8 af[4], bf[4];
#pragma unroll
            for (int rt = 0; rt < 4; ++rt) {
                int row = wr + rt * 16 + l15;
                int pos = (ks * 4 + q) ^ (row & 7);
                af[rt] = *(const bf16x8*)&At[row * 64 + pos * 8];
            }
#pragma unroll
            for (int ct = 0; ct < 4; ++ct) {
                int row = wc + ct * 16 + l15;
                int pos = (ks * 4 + q) ^ (row & 7);
                bf[ct] = *(const bf16x8*)&Bt[row * 64 + pos * 8];
            }
#pragma unroll
            for (int rt = 0; rt < 4; ++rt)
#pragma unroll
                for (int ct = 0; ct < 4; ++ct)
                    acc[rt][ct] = __builtin_amdgcn_mfma_f32_16x16x32_bf16(
                        af[rt], bf[ct], acc[rt][ct], 0, 0, 0);
        }
    }

    float gmm = (MODE == 0) ? gamma_p[0] : 0.f;
#pragma unroll
    for (int rt = 0; rt < 4; ++rt) {
        int nr = n0 + wr + rt * 16 + q * 4;
#pragma unroll
        for (int ct = 0; ct < 4; ++ct) {
            int j = j0 + wc + ct * 16 + l15;
#pragma unroll
            for (int r = 0; r < 4; ++r) {
                float v = acc[rt][ct][r];
                int n = nr + r;
                if (MODE == 1) {
                    Cb[(size_t)n * IOdim + j] = f2bf(v);
                } else if (n < 1024) {
                    int bt = j >> 6, c = j & 63;
                    Cf[(size_t)bt * 65536 + (size_t)n * 64 + c] = gmm * fmaxf(v, 0.f);
                } else {
                    Cb[(size_t)(n - 1024) * Jdim + j] = f2bf(v);
                }
            }
        }
    }
}

// ---------------------------------------------------------------- SA phase 1: L2 = logsumexp_t(S)*log2e (f16)
// Symmetric upper-triangle tiles (L[n,m]=L[m,n]); stores L*log2e so pv's exp becomes
// a single fma + native v_exp_f32 (exp2). Geometry = r10-proven 64x64.
__global__ __launch_bounds__(256, 4) void k_sa_z(
    const short* __restrict__ xbf, short* __restrict__ Lh)
{
    __shared__ short Xn[64 * 64];
    __shared__ short Xm[64 * 64];

    int id = blockIdx.x;
    int b = id & 7;
    int r = id >> 3;                     // 0..135 (upper-tri pair index)
    int tn = 0, rr = r;
    while (rr >= 16 - tn) { rr -= 16 - tn; ++tn; }
    int tm = tn + rr;
    int tid = threadIdx.x;
    int w = tid >> 6, l = tid & 63;
    int l15 = l & 15, q = l >> 4;
    int lrow = l >> 3, lc8 = l & 7;
    int n0 = tn * 64, m0 = tm * 64;
    int wn = (w & 1) * 32, wm = (w >> 1) * 32;

    const short* Xb = xbf + (size_t)b * Tdim * Ndim * Cdim;
    short* Lb = Lh + ((size_t)b << 20);

    f32x4 M[2][2], Z[2][2];
#pragma unroll
    for (int nh = 0; nh < 2; ++nh)
#pragma unroll
        for (int mh = 0; mh < 2; ++mh) { M[nh][mh] = (f32x4)(-INFINITY); Z[nh][mh] = (f32x4)0.f; }

    for (int t = 0; t < Tdim; ++t) {
        const short* xt = Xb + (size_t)t * (Ndim * Cdim);
        __syncthreads();                 // protect prev-iter LDS reads
#pragma unroll
        for (int p = 0; p < 2; ++p) {
            int rw = p * 32 + w * 8 + lrow;
            int sc = lc8 ^ (rw & 7);
            load_lds16(xt + (size_t)(n0 + rw) * 64 + sc * 8, &Xn[(p * 32 + w * 8) * 64]);
            load_lds16(xt + (size_t)(m0 + rw) * 64 + sc * 8, &Xm[(p * 32 + w * 8) * 64]);
        }
        __syncthreads();

        f32x4 sacc[2][2];
        sacc[0][0] = (f32x4)0.f; sacc[0][1] = (f32x4)0.f;
        sacc[1][0] = (f32x4)0.f; sacc[1][1] = (f32x4)0.f;
#pragma unroll
        for (int ch = 0; ch < 2; ++ch) {
            bf16x8 qb[2], af[2];
#pragma unroll
            for (int nh = 0; nh < 2; ++nh) {
                int row = wn + nh * 16 + l15;
                int pos = (ch * 4 + q) ^ (row & 7);
                qb[nh] = *(const bf16x8*)&Xn[row * 64 + pos * 8];
            }
#pragma unroll
            for (int mh = 0; mh < 2; ++mh) {
                int row = wm + mh * 16 + l15;
                int pos = (ch * 4 + q) ^ (row & 7);
                af[mh] = *(const bf16x8*)&Xm[row * 64 + pos * 8];
            }
#pragma unroll
            for (int nh = 0; nh < 2; ++nh)
#pragma unroll
                for (int mh = 0; mh < 2; ++mh)
                    sacc[nh][mh] = __builtin_amdgcn_mfma_f32_16x16x32_bf16(
                        af[mh], qb[nh], sacc[nh][mh], 0, 0, 0);
        }
        // online LSE update
#pragma unroll
        for (int nh = 0; nh < 2; ++nh)
#pragma unroll
            for (int mh = 0; mh < 2; ++mh)
#pragma unroll
                for (int i = 0; i < 4; ++i) {
                    float s  = sacc[nh][mh][i];
                    float mo = M[nh][mh][i];
                    float mn = fmaxf(mo, s);
                    Z[nh][mh][i] = Z[nh][mh][i] * fexp(mo - mn) + fexp(s - mn);
                    M[nh][mh][i] = mn;
                }
    }
#pragma unroll
    for (int nh = 0; nh < 2; ++nh)
#pragma unroll
        for (int mh = 0; mh < 2; ++mh) {
            f16x4 ev;
#pragma unroll
            for (int i = 0; i < 4; ++i)
                ev[i] = (_Float16)fmaf(M[nh][mh][i], LOG2E, __log2f(Z[nh][mh][i]));
            int nn = n0 + wn + nh * 16 + l15;
            int mm = m0 + wm + mh * 16 + q * 4;
            *(f16x4*)&Lb[(size_t)nn * 1024 + mm] = ev;
            if (tn != tm) {
                // transposed write (L symmetric)
#pragma unroll
                for (int i = 0; i < 4; ++i)
                    Lb[(size_t)(mm + i) * 1024 + nn] = ((short*)&ev)[i];
            }
        }
}

// ---------------------------------------------------------------- SA phase 2: out += beta*relu(PV)
// r15: conflicts fixed (8.65M->3.1M) but pv unchanged -> VALU chain is the largest
// measured consumer (31%). This round: (1) p = exp2(fma(S,log2e,-L2)) — 2 ops vs 3;
// (2) v_cvt_pk_bf16_f32 pack (T12 recipe) — 2 ops vs ~12 per 4 values; (3) T5
// setprio(1) around MFMA clusters (3 independent blocks/CU = role diversity).
__global__ __launch_bounds__(256, 3) void k_sa_pv(
    const short* __restrict__ xbf, const short* __restrict__ xT,
    const short* __restrict__ Lh, float* __restrict__ Out,
    const float* __restrict__ beta_p)
{
    __shared__ short Xm[2][64 * 64];     // [buf][m][c], XOR-swizzled granules
    __shared__ short XTl[2][64 * 64];    // [buf][c][m], XOR-swizzled granules
    __shared__ short Pl[4][16 * 64];     // [wave][n][m], XOR-swizzled granules

    int id = blockIdx.x;
    int b = id & 7;
    int r = id >> 3;                     // 0..95
    int nt = r & 7, t = r >> 3;
    int tid = threadIdx.x;
    int w = tid >> 6, l = tid & 63;
    int l15 = l & 15, q = l >> 4;
    int n0 = nt * 128 + w * 32;

    const short* Xb  = xbf + ((size_t)b * Tdim + t) * (Ndim * Cdim);
    const short* XTb = xT  + ((size_t)b * Tdim + t) * (Ndim * Cdim);
    const short* Lb  = Lh + ((size_t)b << 20);

    int srow = tid >> 2, sc4 = tid & 3;  // staging: 64 rows x (2 passes x 4) 16B granules

    // Q B-fragments cached across the m sweep
    bf16x8 qf[2][2];
#pragma unroll
    for (int nh = 0; nh < 2; ++nh)
#pragma unroll
        for (int ch = 0; ch < 2; ++ch)
            qf[nh][ch] = *(const bf16x8*)&Xb[(n0 + nh * 16 + l15) * 64 + ch * 32 + q * 8];

    f32x4 oacc[2][4];
#pragma unroll
    for (int nh = 0; nh < 2; ++nh)
#pragma unroll
        for (int ct = 0; ct < 4; ++ct) oacc[nh][ct] = (f32x4)0.f;

    // preload tile 0 into regs
    bf16x8 v[2], v2[2];
#pragma unroll
    for (int p = 0; p < 2; ++p) {
        v[p]  = *(const bf16x8*)&Xb[(size_t)srow * 64 + (sc4 + 4 * p) * 8];
        v2[p] = *(const bf16x8*)&XTb[(size_t)srow * 1024 + (sc4 + 4 * p) * 8];
    }

    for (int mi = 0; mi < 16; ++mi) {
        int cur = mi & 1;
        int m0 = mi * 64;
        // ---- write tile mi into buf[cur], XOR-swizzled granules
#pragma unroll
        for (int p = 0; p < 2; ++p) {
            int g = sc4 + 4 * p;
            int pos = g ^ (srow & 7);
            *(bf16x8*)&Xm[cur][srow * 64 + pos * 8]  = v[p];
            *(bf16x8*)&XTl[cur][srow * 64 + pos * 8] = v2[p];
        }
        // ---- prefetch tile mi+1 (lands during barrier + compute)
        int m0n = (mi < 15) ? m0 + 64 : m0;
#pragma unroll
        for (int p = 0; p < 2; ++p) {
            v[p]  = *(const bf16x8*)&Xb[(size_t)(m0n + srow) * 64 + (sc4 + 4 * p) * 8];
            v2[p] = *(const bf16x8*)&XTb[(size_t)srow * 1024 + m0n + (sc4 + 4 * p) * 8];
        }
        // ---- e loads for this iter (f16 of L*log2e)
        f16x4 e[2][4];
#pragma unroll
        for (int nh = 0; nh < 2; ++nh)
#pragma unroll
            for (int mh = 0; mh < 4; ++mh)
                e[nh][mh] = *(const f16x4*)&Lb[(size_t)(n0 + nh * 16 + l15) * 1024
                                               + m0 + mh * 16 + q * 4];
        __syncthreads();                 // single barrier per iter

        // ---- scores from Xm[cur] (S[n32][m64])
        f32x4 sacc[2][4];
#pragma unroll
        for (int nh = 0; nh < 2; ++nh)
#pragma unroll
            for (int mh = 0; mh < 4; ++mh) sacc[nh][mh] = (f32x4)0.f;
        __builtin_amdgcn_s_setprio(1);
#pragma unroll
        for (int ch = 0; ch < 2; ++ch) {
#pragma unroll
            for (int mh = 0; mh < 4; ++mh) {
                int row = mh * 16 + l15;
                int pos = (ch * 4 + q) ^ (row & 7);
                bf16x8 af = *(const bf16x8*)&Xm[cur][row * 64 + pos * 8];
                sacc[0][mh] = __builtin_amdgcn_mfma_f32_16x16x32_bf16(
                    af, qf[0][ch], sacc[0][mh], 0, 0, 0);
                sacc[1][mh] = __builtin_amdgcn_mfma_f32_16x16x32_bf16(
                    af, qf[1][ch], sacc[1][mh], 0, 0, 0);
            }
        }
        __builtin_amdgcn_s_setprio(0);
        // ---- per nh: p = exp2(fma(S,log2e,-L2)), cvt_pk pack -> Pl -> PV
#pragma unroll
        for (int nh = 0; nh < 2; ++nh) {
#pragma unroll
            for (int mh = 0; mh < 4; ++mh) {
                f32x4 p = sacc[nh][mh];
                f16x4 ee = e[nh][mh];
                float x0 = exp2f(fmaf(p[0], LOG2E, -(float)ee[0]));
                float x1 = exp2f(fmaf(p[1], LOG2E, -(float)ee[1]));
                float x2 = exp2f(fmaf(p[2], LOG2E, -(float)ee[2]));
                float x3 = exp2f(fmaf(p[3], LOG2E, -(float)ee[3]));
                unsigned u0 = pk_bf16(x0, x1);
                unsigned u1 = pk_bf16(x2, x3);
                // granule of m = mh*16 + q*4 is g = mh*2 + (q>>1); in-granule ofs (q&1)*4
                int g = mh * 2 + (q >> 1);
                int pos = g ^ (l15 & 7);
                *(uint2*)&Pl[w][l15 * 64 + pos * 8 + (q & 1) * 4] = make_uint2(u0, u1);
            }
            __builtin_amdgcn_s_setprio(1);
#pragma unroll
            for (int ks = 0; ks < 2; ++ks) {
                int gr = ks * 4 + q;
                int pos = gr ^ (l15 & 7);
                bf16x8 pf = *(const bf16x8*)&Pl[w][l15 * 64 + pos * 8];
#pragma unroll
                for (int ct = 0; ct < 4; ++ct) {
                    int row = ct * 16 + l15;
                    int bp = (ks * 4 + q) ^ (row & 7);
                    bf16x8 bfr = *(const bf16x8*)&XTl[cur][row * 64 + bp * 8];
                    oacc[nh][ct] = __builtin_amdgcn_mfma_f32_16x16x32_bf16(
                        pf, bfr, oacc[nh][ct], 0, 0, 0);
                }
            }
            __builtin_amdgcn_s_setprio(0);
        }
    }

    float beta = beta_p[0];
#pragma unroll
    for (int nh = 0; nh < 2; ++nh)
#pragma unroll
        for (int ct = 0; ct < 4; ++ct)
#pragma unroll
            for (int r2 = 0; r2 < 4; ++r2) {
                size_t idx = (((size_t)b * Tdim + t) * Ndim + n0 + nh * 16 + q * 4 + r2) * Cdim
                           + ct * 16 + l15;
                Out[idx] += beta * fmaxf(oacc[nh][ct][r2], 0.f);
            }
}

// ---------------------------------------------------------------- bias = S @ bpool via MFMA
__global__ __launch_bounds__(256) void k_bias(
    const short* __restrict__ Sbf, const short* __restrict__ bpT,
    float* __restrict__ bias)
{
    int tid = threadIdx.x;
    int w = tid >> 6, l = tid & 63;
    int l15 = l & 15, q = l >> 4;
    int nr = blockIdx.x * 64 + w * 16;

    f32x4 acc[4];
#pragma unroll
    for (int ct = 0; ct < 4; ++ct) acc[ct] = (f32x4)0.f;

    for (int k0 = 0; k0 < 1024; k0 += 32) {
        bf16x8 af = *(const bf16x8*)&Sbf[(size_t)(nr + l15) * 1024 + k0 + q * 8];
#pragma unroll
        for (int ct = 0; ct < 4; ++ct) {
            bf16x8 bf = *(const bf16x8*)&bpT[(size_t)(ct * 16 + l15) * 1024 + k0 + q * 8];
            acc[ct] = __builtin_amdgcn_mfma_f32_16x16x32_bf16(af, bf, acc[ct], 0, 0, 0);
        }
    }
#pragma unroll
    for (int ct = 0; ct < 4; ++ct)
#pragma unroll
        for (int r = 0; r < 4; ++r)
            bias[(size_t)(nr + q * 4 + r) * 64 + ct * 16 + l15] = acc[ct][r];
}

// ---------------------------------------------------------------- gconv via MFMA (6 waves)
__global__ __launch_bounds__(384) void k_gconv(
    const short* __restrict__ xgT, const short* __restrict__ Wb,
    const float* __restrict__ bias, float* __restrict__ Out,
    const float* __restrict__ alpha_p)
{
    __shared__ short Wl[64 * 64];
    int n = blockIdx.x;
    int tid = threadIdx.x;
    for (int f = tid; f < 512; f += 384) {
        int k = f >> 3, j = f & 7;
        *(bf16x8*)&Wl[k * 64 + (j ^ ((k >> 3) & 7)) * 8] =
            *(const bf16x8*)&Wb[(size_t)n * IOdim + f * 8];
    }
    __syncthreads();
    int w = tid / 64, l = tid & 63, l15 = l & 15, q = l >> 4;
    f32x4 acc[4];
#pragma unroll
    for (int ct = 0; ct < 4; ++ct) acc[ct] = (f32x4)0.f;
    const short* xr = xgT + (size_t)n * Jdim + (size_t)(w * 16 + l15) * 64;
#pragma unroll
    for (int ks = 0; ks < 2; ++ks) {
        bf16x8 a = *(const bf16x8*)&xr[ks * 32 + q * 8];
        int kb = ks * 32 + q * 8;
        int msk = (kb >> 3) & 7;
#pragma unroll
        for (int ct = 0; ct < 4; ++ct) {
            bf16x8 bfr;
#pragma unroll
            for (int e = 0; e < 8; ++e) {
                int o = ct * 16 + l15;
                bfr[e] = Wl[(kb + e) * 64 + (((o >> 3) ^ msk) * 8) + (o & 7)];
            }
            acc[ct] = __builtin_amdgcn_mfma_f32_16x16x32_bf16(a, bfr, acc[ct], 0, 0, 0);
        }
    }
    float alpha = alpha_p[0];
#pragma unroll
    for (int ct = 0; ct < 4; ++ct) {
        int o = ct * 16 + l15;
        float bo = bias[(size_t)n * 64 + o];
#pragma unroll
        for (int r = 0; r < 4; ++r) {
            int bt = w * 16 + q * 4 + r;
            size_t idx = (size_t)bt * 65536 + (size_t)n * 64 + o;
            Out[idx] += alpha * fmaxf(acc[ct][r] + bo, 0.f);
        }
    }
}

// ---------------------------------------------------------------- launch
extern "C" void kernel_launch(void* const* d_in, const int* in_sizes, int n_in,
                              void* d_out, int out_size, void* d_ws, size_t ws_size,
                              hipStream_t stream)
{
    const float* x     = (const float*)d_in[0];
    const float* e1    = (const float*)d_in[1];
    const float* e2    = (const float*)d_in[2];
    const float* Asym  = (const float*)d_in[3];
    const float* wpool = (const float*)d_in[4];
    const float* bpool = (const float*)d_in[5];
    const float* alpha = (const float*)d_in[6];
    const float* beta  = (const float*)d_in[7];
    const float* gamma = (const float*)d_in[8];
    float* out = (float*)d_out;

    short* ASbf = (short*)d_ws;                       // 2048x1024   (4 MB)
    short* xbf  = ASbf + 2048 * 1024;                 // 12.6 MB
    short* xT   = xbf  + 6291456;                     // 12.6 MB
    short* wpT  = xT   + 6291456;                     // 8.4 MB
    short* Wbf  = wpT  + 4194304;                     // 8.4 MB
    short* xgT  = Wbf  + 4194304;                     // 12.6 MB
    float* bias = (float*)(xgT + 6291456);            // 256 KB
    short* Lh   = (short*)(bias + 65536);             // 16.8 MB (logsumexp*log2e, f16)
    short* bpT  = Lh + 8388608;                       // 128 KB (bpool^T bf16)

    // fused: supports (0..4095) + softmax rows (4096..5119) + bpT (5120..5135)
    k_prep<<<5136, 256, 0, stream>>>(e1, e2, ASbf + 1024 * 1024, Asym, ASbf, bpool, bpT);
    // fused: x->xbf/xT (0..1535) + wpool->wpT (1536..2559)
    k_cvt2<<<2560, 256, 0, stream>>>(x, xbf, xT, wpool, wpT);
    // SA phase 1: symmetric upper-triangle tiles, L*log2e f16 out
    k_sa_z<<<1088, 256, 0, stream>>>(xbf, Lh);
    // stacked: rows 0..1023 -> out = gamma*relu(A@x); rows 1024..2047 -> xgT = S@x
    k_gemm_bt<0><<<768, 256, 0, stream>>>(ASbf, xT, out, xgT, gamma);
    // Wbf = S @ wpool
    k_gemm_bt<1><<<256, 256, 0, stream>>>(ASbf + 1024 * 1024, wpT, nullptr, Wbf, nullptr);
    // bias = S @ bpool (MFMA, L2-resident)
    k_bias<<<16, 256, 0, stream>>>(ASbf + 1024 * 1024, bpT, bias);
    // SA phase 2: out += beta*relu(PV); exp2+cvt_pk+setprio
    k_sa_pv<<<768, 256, 0, stream>>>(xbf, xT, Lh, out, beta);
    // out += alpha * relu(xgT @ W[n] + bias[n])
    k_gconv<<<1024, 384, 0, stream>>>(xgT, Wbf, bias, out, alpha);
}